// Round 17
// baseline (177.449 us; speedup 1.0000x reference)
//
#include <hip/hip_runtime.h>
#include <hip/hip_bf16.h>
#include <stdint.h>

// B=2, T=4096, C=512, H=8, D=64. Inputs fp32, output fp32, internals bf16.
// ws (bf16 elems), 32 MiB:
//   Q  [0        .. 4194304)   [B,H,T,D]  (pre-scaled by 0.125*log2e)
//   K  [4194304  .. 8388608)   [B,H,T,D]
//   Vt [8388608  .. 12582912)  [B,H,D,T]
//   Y  [12582912 .. 16777216)  [B,T,C]    (WaT here during QKV; clobbered by attn)
// WpT -> Q region after attn (Q dead). xb (x bf16) in d_out until proj overwrites.

typedef __attribute__((ext_vector_type(8))) short short8;
typedef __attribute__((ext_vector_type(4))) float floatx4;

__device__ __forceinline__ unsigned short f2bf(float f) {
    unsigned int x = __float_as_uint(f);
    unsigned int r = x + 0x7fffu + ((x >> 16) & 1u);
    return (unsigned short)(r >> 16);
}

__device__ __forceinline__ unsigned int pk_bf16(float a, float b) {
    __hip_bfloat162 p = __float22bfloat162_rn(make_float2(a, b));  // v_cvt_pk_bf16_f32
    return *reinterpret_cast<unsigned int*>(&p);
}

// ---------------- P0: fused prep: convert x (blocks 0..2047) + W_attn^T (2048..2815) --
__global__ __launch_bounds__(256) void prep_a(
    const float* __restrict__ x, unsigned short* __restrict__ xb,
    const float* __restrict__ Wa, unsigned short* __restrict__ WaT)
{
    const int bid = blockIdx.x;
    const int tid = threadIdx.x;
    if (bid < 2048) {
        size_t i = ((size_t)bid * 256 + tid) * 8;
        float4 a = *reinterpret_cast<const float4*>(x + i);
        float4 b = *reinterpret_cast<const float4*>(x + i + 4);
        unsigned short o[8] = {f2bf(a.x), f2bf(a.y), f2bf(a.z), f2bf(a.w),
                               f2bf(b.x), f2bf(b.y), f2bf(b.z), f2bf(b.w)};
        *reinterpret_cast<uint4*>(xb + i) = *reinterpret_cast<uint4*>(o);
    } else {
        __shared__ unsigned short tile[32][34];
        const int t2 = bid - 2048;           // 48 n-tiles x 16 k-tiles
        const int n0 = (t2 % 48) * 32, k0 = (t2 / 48) * 32;
        const int tx = tid & 31, ty = tid >> 5;
        #pragma unroll
        for (int p = 0; p < 4; ++p)
            tile[tx][ty + p * 8] = f2bf(Wa[(size_t)(k0 + ty + p * 8) * 1536 + n0 + tx]);
        __syncthreads();
        #pragma unroll
        for (int p = 0; p < 4; ++p)
            WaT[(size_t)(n0 + ty + p * 8) * 512 + k0 + tx] = tile[ty + p * 8][tx];
    }
}

// ---------------- P1: W_proj [512][512] fp32 -> WpT [512][512] bf16 -------------------
__global__ __launch_bounds__(256) void transpose_wp(
    const float* __restrict__ W, unsigned short* __restrict__ Wt)
{
    __shared__ unsigned short tile[32][34];
    const int tid = threadIdx.x;
    const int tx = tid & 31, ty = tid >> 5;
    const int n0 = blockIdx.x * 32, k0 = blockIdx.y * 32;
    #pragma unroll
    for (int p = 0; p < 4; ++p)
        tile[tx][ty + p * 8] = f2bf(W[(size_t)(k0 + ty + p * 8) * 512 + n0 + tx]);
    __syncthreads();
    #pragma unroll
    for (int p = 0; p < 4; ++p)
        Wt[(size_t)(n0 + ty + p * 8) * 512 + k0 + tx] = tile[ty + p * 8][tx];
}

// ---------------- QKV GEMM: 128m x 64n tile, BK=32, LDS dbuf, 1 barrier/iter ----------
// Grid (m=64, n=24) m-fastest (XCD-local A reuse); 1536 blocks -> ~5/CU (30.7 KB LDS).
// Each block covers exactly ONE head (64-wide tile) -> uniform epilogue.
// Buffers: A0@0(10240) B0@10240(5120) A1@15360 B1@25600. Tr epilogue reuses smem.
__global__ __launch_bounds__(256) void mm_qkv(
    const unsigned short* __restrict__ A,
    const unsigned short* __restrict__ Bt,
    unsigned short* __restrict__ WS)
{
    __shared__ __align__(16) unsigned char smem[30720];

    const int tid  = threadIdx.x;
    const int wave = tid >> 6;
    const int lane = tid & 63;
    const int quad = lane >> 4;
    const int l16  = lane & 15;
    const int wr   = wave >> 1;     // 0..1 : 64-row half
    const int wc   = wave & 1;      // 0..1 : 32-col half
    const int m0 = blockIdx.x * 128;
    const int n0 = blockIdx.y * 64;

    floatx4 acc[4][2];
    #pragma unroll
    for (int i = 0; i < 4; ++i)
        #pragma unroll
        for (int j = 0; j < 2; ++j) acc[i][j] = (floatx4){0.f, 0.f, 0.f, 0.f};

    const int arow = tid >> 1, acb = (tid & 1) * 16;   // A: 2 x uint4 / thread
    const int brow = tid >> 2, bcb = (tid & 3) * 8;    // B: 1 x uint4 / thread

    const unsigned short* ap = &A [(size_t)(m0 + arow) * 512 + acb];
    const unsigned short* bp = &Bt[(size_t)(n0 + brow) * 512 + bcb];

    uint4 ra0 = *reinterpret_cast<const uint4*>(ap);
    uint4 ra1 = *reinterpret_cast<const uint4*>(ap + 8);
    uint4 rb0 = *reinterpret_cast<const uint4*>(bp);
    {
        auto Al = reinterpret_cast<unsigned short(*)[40]>(smem);
        auto Bl = reinterpret_cast<unsigned short(*)[40]>(smem + 10240);
        *reinterpret_cast<uint4*>(&Al[arow][acb])     = ra0;
        *reinterpret_cast<uint4*>(&Al[arow][acb + 8]) = ra1;
        *reinterpret_cast<uint4*>(&Bl[brow][bcb])     = rb0;
    }

    for (int it = 0; it < 16; ++it) {
        __syncthreads();
        const int k0 = it * 32;
        if (it < 15) {
            ra0 = *reinterpret_cast<const uint4*>(ap + k0 + 32);
            ra1 = *reinterpret_cast<const uint4*>(ap + k0 + 40);
            rb0 = *reinterpret_cast<const uint4*>(bp + k0 + 32);
        }

        auto Al = reinterpret_cast<unsigned short(*)[40]>(smem + (it & 1) * 15360);
        auto Bl = reinterpret_cast<unsigned short(*)[40]>(smem + (it & 1) * 15360 + 10240);

        short8 af[4], bf[2];
        #pragma unroll
        for (int ti = 0; ti < 4; ++ti)
            af[ti] = *reinterpret_cast<const short8*>(&Al[wr * 64 + ti * 16 + l16][quad * 8]);
        #pragma unroll
        for (int tj = 0; tj < 2; ++tj)
            bf[tj] = *reinterpret_cast<const short8*>(&Bl[wc * 32 + tj * 16 + l16][quad * 8]);
        #pragma unroll
        for (int ti = 0; ti < 4; ++ti)
            #pragma unroll
            for (int tj = 0; tj < 2; ++tj)
                acc[ti][tj] = __builtin_amdgcn_mfma_f32_16x16x32_bf16(af[ti], bf[tj], acc[ti][tj], 0, 0, 0);

        if (it < 15) {
            auto An = reinterpret_cast<unsigned short(*)[40]>(smem + ((it + 1) & 1) * 15360);
            auto Bn = reinterpret_cast<unsigned short(*)[40]>(smem + ((it + 1) & 1) * 15360 + 10240);
            *reinterpret_cast<uint4*>(&An[arow][acb])     = ra0;
            *reinterpret_cast<uint4*>(&An[arow][acb + 8]) = ra1;
            *reinterpret_cast<uint4*>(&Bn[brow][bcb])     = rb0;
        }
    }

    unsigned short* Qb  = WS;
    unsigned short* Kb  = WS + 4194304;
    unsigned short* Vtb = WS + 8388608;
    const int which = n0 >> 9;           // block-uniform
    const int h = (n0 >> 6) & 7;         // block-uniform (64-wide tile = one head)
    const int b = m0 >> 12;              // block-uniform batch
    const int bh = b * 8 + h;

    if (which == 2) {
        // Vt: per-wave 64t x 32d LDS transpose -> coalesced b128 stores along t
        auto Tr = reinterpret_cast<unsigned short(*)[72]>(smem);   // [128][72] (d-rows)
        __syncthreads();   // staging buffers dead
        #pragma unroll
        for (int ti = 0; ti < 4; ++ti)
            #pragma unroll
            for (int tj = 0; tj < 2; ++tj) {
                unsigned int lo = pk_bf16(acc[ti][tj][0], acc[ti][tj][1]);
                unsigned int hi = pk_bf16(acc[ti][tj][2], acc[ti][tj][3]);
                // row = wave's d (32) ; col = t-local (64), 4 consecutive t
                *reinterpret_cast<uint2*>(&Tr[wave * 32 + tj * 16 + l16][ti * 16 + quad * 4])
                    = make_uint2(lo, hi);
            }
        const int t0g = (m0 & 4095) + wr * 64;
        const int tseg = (lane & 7) * 8;
        #pragma unroll
        for (int p = 0; p < 4; ++p) {
            int dl = p * 8 + (lane >> 3);      // 0..31 within wave's d-half
            uint4 v = *reinterpret_cast<const uint4*>(&Tr[wave * 32 + dl][tseg]);
            *reinterpret_cast<uint4*>(&Vtb[((size_t)(bh * 64 + wc * 32 + dl)) * 4096 + t0g + tseg]) = v;
        }
    } else {
        const float sc = (which == 0) ? 0.18033688f : 1.0f;  // 0.125*log2(e)
        unsigned short* Ob = (which == 0) ? Qb : Kb;
        #pragma unroll
        for (int ti = 0; ti < 4; ++ti) {
            #pragma unroll
            for (int r = 0; r < 4; ++r) {
                int m = m0 + wr * 64 + ti * 16 + quad * 4 + r;
                int t = m & 4095;
                #pragma unroll
                for (int tj = 0; tj < 2; ++tj) {
                    int d = wc * 32 + tj * 16 + l16;
                    Ob[((size_t)bh * 4096 + t) * 64 + d] = f2bf(acc[ti][tj][r] * sc);
                }
            }
        }
    }
}

// ---------------- Proj GEMM: 64x64 tile, BK=32, LDS dbuf; grid 128x8 = 1024 blocks ----
// 4 waves 2x2, wave tile 32x32. LDS 20.5 KB -> grid-bound 4 blocks/CU (was 1/CU).
__global__ __launch_bounds__(256) void mm_proj(
    const unsigned short* __restrict__ A,
    const unsigned short* __restrict__ Bt,
    float* __restrict__ Out)
{
    __shared__ __align__(16) unsigned char smem[20480];

    const int tid  = threadIdx.x;
    const int wave = tid >> 6;
    const int lane = tid & 63;
    const int quad = lane >> 4;
    const int l16  = lane & 15;
    const int wr   = wave >> 1;
    const int wc   = wave & 1;
    const int m0 = blockIdx.x * 64;
    const int n0 = blockIdx.y * 64;

    floatx4 acc[2][2];
    #pragma unroll
    for (int i = 0; i < 2; ++i)
        #pragma unroll
        for (int j = 0; j < 2; ++j) acc[i][j] = (floatx4){0.f, 0.f, 0.f, 0.f};

    const int row = tid >> 2, cb = (tid & 3) * 8;   // 64x32 tile: 1 uint4 / thread

    const unsigned short* ap = &A [(size_t)(m0 + row) * 512 + cb];
    const unsigned short* bp = &Bt[(size_t)(n0 + row) * 512 + cb];

    uint4 ra = *reinterpret_cast<const uint4*>(ap);
    uint4 rb = *reinterpret_cast<const uint4*>(bp);
    {
        auto Al = reinterpret_cast<unsigned short(*)[40]>(smem);
        auto Bl = reinterpret_cast<unsigned short(*)[40]>(smem + 5120);
        *reinterpret_cast<uint4*>(&Al[row][cb]) = ra;
        *reinterpret_cast<uint4*>(&Bl[row][cb]) = rb;
    }

    for (int it = 0; it < 16; ++it) {
        __syncthreads();
        const int k0 = it * 32;
        if (it < 15) {
            ra = *reinterpret_cast<const uint4*>(ap + k0 + 32);
            rb = *reinterpret_cast<const uint4*>(bp + k0 + 32);
        }

        auto Al = reinterpret_cast<unsigned short(*)[40]>(smem + (it & 1) * 10240);
        auto Bl = reinterpret_cast<unsigned short(*)[40]>(smem + (it & 1) * 10240 + 5120);

        short8 af[2], bf[2];
        #pragma unroll
        for (int ti = 0; ti < 2; ++ti)
            af[ti] = *reinterpret_cast<const short8*>(&Al[wr * 32 + ti * 16 + l16][quad * 8]);
        #pragma unroll
        for (int tj = 0; tj < 2; ++tj)
            bf[tj] = *reinterpret_cast<const short8*>(&Bl[wc * 32 + tj * 16 + l16][quad * 8]);
        #pragma unroll
        for (int ti = 0; ti < 2; ++ti)
            #pragma unroll
            for (int tj = 0; tj < 2; ++tj)
                acc[ti][tj] = __builtin_amdgcn_mfma_f32_16x16x32_bf16(af[ti], bf[tj], acc[ti][tj], 0, 0, 0);

        if (it < 15) {
            auto An = reinterpret_cast<unsigned short(*)[40]>(smem + ((it + 1) & 1) * 10240);
            auto Bn = reinterpret_cast<unsigned short(*)[40]>(smem + ((it + 1) & 1) * 10240 + 5120);
            *reinterpret_cast<uint4*>(&An[row][cb]) = ra;
            *reinterpret_cast<uint4*>(&Bn[row][cb]) = rb;
        }
    }

    #pragma unroll
    for (int ti = 0; ti < 2; ++ti)
        #pragma unroll
        for (int r = 0; r < 4; ++r) {
            int m = m0 + wr * 32 + ti * 16 + quad * 4 + r;
            #pragma unroll
            for (int tj = 0; tj < 2; ++tj) {
                int n = n0 + wc * 32 + tj * 16 + l16;
                Out[(size_t)m * 512 + n] = acc[ti][tj][r];
            }
        }
}

// ---------------- MFMA flash attention (r15 proven, 75 us): 16 q-rows/wave ------------
__global__ __launch_bounds__(256) void attn_mfma(
    const unsigned short* __restrict__ Q,
    const unsigned short* __restrict__ K,
    const unsigned short* __restrict__ Vt,
    unsigned short* __restrict__ Y)
{
    __shared__ __align__(16) unsigned short Kc[64][72];
    __shared__ __align__(16) unsigned short Vc[64][72];
    __shared__ __align__(16) unsigned short Pc[4][16][72];

    const int tid  = threadIdx.x;
    const int wave = tid >> 6;
    const int lane = tid & 63;
    const int quad = lane >> 4;
    const int l16  = lane & 15;

    const int bid = blockIdx.x;
    const int bh = bid & 15;
    const int j  = (bid >> 4) & 15;
    const int g  = bid >> 8;
    const int qb = (g == 0) ? j : (g == 1) ? (63 - j) : (g == 2) ? (16 + j) : (47 - j);
    const int m0 = qb * 64;

    const unsigned short* Qp = Q  + (size_t)bh * (4096 * 64);
    const unsigned short* Kp = K  + (size_t)bh * (4096 * 64);
    const unsigned short* Vp = Vt + (size_t)bh * (64 * 4096);

    const int qrow = m0 + wave * 16 + l16;
    short8 qf[2];
    qf[0] = *reinterpret_cast<const short8*>(&Qp[(size_t)qrow * 64 + quad * 8]);
    qf[1] = *reinterpret_cast<const short8*>(&Qp[(size_t)qrow * 64 + 32 + quad * 8]);

    short8 ones;
    #pragma unroll
    for (int i = 0; i < 8; ++i) ones[i] = (short)0x3F80;

    floatx4 o[4] = {{0,0,0,0},{0,0,0,0},{0,0,0,0},{0,0,0,0}};
    floatx4 o4 = {0, 0, 0, 0};

    const int r0 = tid >> 3,          c0 = (tid & 7) * 8;
    const int r1 = (tid + 256) >> 3,  c1 = c0;

    uint4 rk0 = *reinterpret_cast<const uint4*>(&Kp[(size_t)r0 * 64 + c0]);
    uint4 rk1 = *reinterpret_cast<const uint4*>(&Kp[(size_t)r1 * 64 + c1]);
    uint4 rv0 = *reinterpret_cast<const uint4*>(&Vp[(size_t)r0 * 4096 + c0]);
    uint4 rv1 = *reinterpret_cast<const uint4*>(&Vp[(size_t)r1 * 4096 + c1]);

    for (int kt = 0; kt <= qb; ++kt) {
        __syncthreads();
        *reinterpret_cast<uint4*>(&Kc[r0][c0]) = rk0;
        *reinterpret_cast<uint4*>(&Kc[r1][c1]) = rk1;
        *reinterpret_cast<uint4*>(&Vc[r0][c0]) = rv0;
        *reinterpret_cast<uint4*>(&Vc[r1][c1]) = rv1;
        __syncthreads();

        if (kt < qb) {
            const int jn = (kt + 1) * 64;
            rk0 = *reinterpret_cast<const uint4*>(&Kp[(size_t)(jn + r0) * 64 + c0]);
            rk1 = *reinterpret_cast<const uint4*>(&Kp[(size_t)(jn + r1) * 64 + c1]);
            rv0 = *reinterpret_cast<const uint4*>(&Vp[(size_t)r0 * 4096 + jn + c0]);
            rv1 = *reinterpret_cast<const uint4*>(&Vp[(size_t)r1 * 4096 + jn + c1]);
        }

        float sv[4][4];
        #pragma unroll
        for (int ct = 0; ct < 4; ++ct) {
            floatx4 s = {0, 0, 0, 0};
            #pragma unroll
            for (int kk = 0; kk < 2; ++kk) {
                short8 a = *reinterpret_cast<const short8*>(&Kc[ct * 16 + l16][kk * 32 + quad * 8]);
                s = __builtin_amdgcn_mfma_f32_16x16x32_bf16(a, qf[kk], s, 0, 0, 0);
            }
            sv[ct][0] = s[0]; sv[ct][1] = s[1]; sv[ct][2] = s[2]; sv[ct][3] = s[3];
        }

        if (kt == qb) {
            #pragma unroll
            for (int ct = 0; ct < 4; ++ct)
                #pragma unroll
                for (int r = 0; r < 4; ++r) {
                    int keyl = ct * 16 + quad * 4 + r;
                    int ql   = wave * 16 + l16;
                    sv[ct][r] = (keyl <= ql) ? sv[ct][r] : -1e30f;
                }
        }
        #pragma unroll
        for (int ct = 0; ct < 4; ++ct)
            #pragma unroll
            for (int r = 0; r < 4; ++r)
                sv[ct][r] = __builtin_amdgcn_exp2f(sv[ct][r]);

        #pragma unroll
        for (int ct = 0; ct < 4; ++ct) {
            unsigned int d0 = pk_bf16(sv[ct][0], sv[ct][1]);
            unsigned int d1 = pk_bf16(sv[ct][2], sv[ct][3]);
            *reinterpret_cast<uint2*>(&Pc[wave][l16][ct * 16 + quad * 4]) = make_uint2(d0, d1);
        }

        short8 pa[2];
        pa[0] = *reinterpret_cast<const short8*>(&Pc[wave][l16][quad * 8]);
        pa[1] = *reinterpret_cast<const short8*>(&Pc[wave][l16][32 + quad * 8]);

        #pragma unroll
        for (int kk = 0; kk < 2; ++kk)
            o4 = __builtin_amdgcn_mfma_f32_16x16x32_bf16(pa[kk], ones, o4, 0, 0, 0);
        #pragma unroll
        for (int n = 0; n < 4; ++n) {
            #pragma unroll
            for (int kk = 0; kk < 2; ++kk) {
                short8 b = *reinterpret_cast<const short8*>(&Vc[n * 16 + l16][kk * 32 + quad * 8]);
                o[n] = __builtin_amdgcn_mfma_f32_16x16x32_bf16(pa[kk], b, o[n], 0, 0, 0);
            }
        }
    }

    const int b = bh >> 3, h = bh & 7;
    #pragma unroll
    for (int r = 0; r < 4; ++r) {
        float inv = 1.0f / o4[r];
        int t = m0 + wave * 16 + quad * 4 + r;
        #pragma unroll
        for (int n = 0; n < 4; ++n)
            Y[((size_t)(b * 4096 + t)) * 512 + h * 64 + n * 16 + l16] = f2bf(o[n][r] * inv);
    }
}

extern "C" void kernel_launch(void* const* d_in, const int* in_sizes, int n_in,
                              void* d_out, int out_size, void* d_ws, size_t ws_size,
                              hipStream_t stream) {
    const float* x  = (const float*)d_in[0];
    const float* Wa = (const float*)d_in[1];
    const float* Wp = (const float*)d_in[2];
    float* out = (float*)d_out;
    unsigned short* ws = (unsigned short*)d_ws;

    unsigned short* Qb  = ws;
    unsigned short* Kb  = ws + 4194304;
    unsigned short* Vtb = ws + 8388608;
    unsigned short* Yb  = ws + 12582912;
    unsigned short* WaT = Yb;                      // W_attn^T during QKV only
    unsigned short* WpT = Qb;                      // W_proj^T after attn (Q dead)
    unsigned short* xb  = (unsigned short*)d_out;  // x bf16; overwritten by proj

    prep_a<<<dim3(2816), dim3(256), 0, stream>>>(x, xb, Wa, WaT);
    mm_qkv<<<dim3(64, 24), dim3(256), 0, stream>>>(xb, WaT, ws);
    attn_mfma<<<dim3(1024), dim3(256), 0, stream>>>(Qb, Kb, Vtb, Yb);
    transpose_wp<<<dim3(16, 16), dim3(256), 0, stream>>>(Wp, WpT);
    mm_proj<<<dim3(128, 8), dim3(256), 0, stream>>>(Yb, WpT, out);
}

// Round 18
// 171.488 us; speedup vs baseline: 1.0348x; 1.0348x over previous
//
#include <hip/hip_runtime.h>
#include <hip/hip_bf16.h>
#include <stdint.h>

// B=2, T=4096, C=512, H=8, D=64. Inputs fp32, output fp32, internals bf16.
// ws (bf16 elems), 32 MiB:
//   Q  [0        .. 4194304)   [B,H,T,D]  (pre-scaled by 0.125*log2e)
//   K  [4194304  .. 8388608)   [B,H,T,D]
//   Vt [8388608  .. 12582912)  [B,H,D,T]
//   Y  [12582912 .. 16777216)  [B,T,C]    (WaT here during QKV; clobbered by attn)
// WpT -> Q region after attn (Q dead). xb (x bf16) in d_out until proj overwrites.

typedef __attribute__((ext_vector_type(8))) short short8;
typedef __attribute__((ext_vector_type(4))) float floatx4;

__device__ __forceinline__ unsigned short f2bf(float f) {
    unsigned int x = __float_as_uint(f);
    unsigned int r = x + 0x7fffu + ((x >> 16) & 1u);
    return (unsigned short)(r >> 16);
}

__device__ __forceinline__ unsigned int pk_bf16(float a, float b) {
    __hip_bfloat162 p = __float22bfloat162_rn(make_float2(a, b));  // v_cvt_pk_bf16_f32
    return *reinterpret_cast<unsigned int*>(&p);
}

// ---------------- P0: fused prep: convert x (blocks 0..2047) + W_attn^T (2048..2815) --
__global__ __launch_bounds__(256) void prep_a(
    const float* __restrict__ x, unsigned short* __restrict__ xb,
    const float* __restrict__ Wa, unsigned short* __restrict__ WaT)
{
    const int bid = blockIdx.x;
    const int tid = threadIdx.x;
    if (bid < 2048) {
        size_t i = ((size_t)bid * 256 + tid) * 8;
        float4 a = *reinterpret_cast<const float4*>(x + i);
        float4 b = *reinterpret_cast<const float4*>(x + i + 4);
        unsigned short o[8] = {f2bf(a.x), f2bf(a.y), f2bf(a.z), f2bf(a.w),
                               f2bf(b.x), f2bf(b.y), f2bf(b.z), f2bf(b.w)};
        *reinterpret_cast<uint4*>(xb + i) = *reinterpret_cast<uint4*>(o);
    } else {
        __shared__ unsigned short tile[32][34];
        const int t2 = bid - 2048;           // 48 n-tiles x 16 k-tiles
        const int n0 = (t2 % 48) * 32, k0 = (t2 / 48) * 32;
        const int tx = tid & 31, ty = tid >> 5;
        #pragma unroll
        for (int p = 0; p < 4; ++p)
            tile[tx][ty + p * 8] = f2bf(Wa[(size_t)(k0 + ty + p * 8) * 1536 + n0 + tx]);
        __syncthreads();
        #pragma unroll
        for (int p = 0; p < 4; ++p)
            WaT[(size_t)(n0 + ty + p * 8) * 512 + k0 + tx] = tile[ty + p * 8][tx];
    }
}

// ---------------- P1: W_proj [512][512] fp32 -> WpT [512][512] bf16 -------------------
__global__ __launch_bounds__(256) void transpose_wp(
    const float* __restrict__ W, unsigned short* __restrict__ Wt)
{
    __shared__ unsigned short tile[32][34];
    const int tid = threadIdx.x;
    const int tx = tid & 31, ty = tid >> 5;
    const int n0 = blockIdx.x * 32, k0 = blockIdx.y * 32;
    #pragma unroll
    for (int p = 0; p < 4; ++p)
        tile[tx][ty + p * 8] = f2bf(W[(size_t)(k0 + ty + p * 8) * 512 + n0 + tx]);
    __syncthreads();
    #pragma unroll
    for (int p = 0; p < 4; ++p)
        Wt[(size_t)(n0 + ty + p * 8) * 512 + k0 + tx] = tile[ty + p * 8][tx];
}

// ---------------- MFMA GEMM (r16-proven): 128x128, BK=32, LDS dbuf, 1 barrier/iter ----
// Buffers: A0@0, B0@10240, A1@20480, B1@30720. Grid (m,n) m-fastest (XCD-local A).
// EPI 0: Q/K direct + Vt LDS-transposed (Tr reuses smem). EPI 1: fp32 store.
template<int EPI>
__global__ __launch_bounds__(256) void mm_bt(
    const unsigned short* __restrict__ A,
    const unsigned short* __restrict__ Bt,
    void* __restrict__ outp)
{
    __shared__ __align__(16) unsigned char smem[40960];

    const int tid  = threadIdx.x;
    const int wave = tid >> 6;
    const int lane = tid & 63;
    const int quad = lane >> 4;
    const int l16  = lane & 15;
    const int wr   = wave >> 1;
    const int wc   = wave & 1;
    const int m0 = blockIdx.x * 128;
    const int n0 = blockIdx.y * 128;

    floatx4 acc[4][4];
    #pragma unroll
    for (int i = 0; i < 4; ++i)
        #pragma unroll
        for (int j = 0; j < 4; ++j) acc[i][j] = (floatx4){0.f, 0.f, 0.f, 0.f};

    const int row = tid >> 1;
    const int cb  = (tid & 1) * 16;

    const unsigned short* ap = &A[(size_t)(m0 + row) * 512 + cb];
    const unsigned short* bp = &Bt[(size_t)(n0 + row) * 512 + cb];

    uint4 ra0 = *reinterpret_cast<const uint4*>(ap);
    uint4 ra1 = *reinterpret_cast<const uint4*>(ap + 8);
    uint4 rb0 = *reinterpret_cast<const uint4*>(bp);
    uint4 rb1 = *reinterpret_cast<const uint4*>(bp + 8);
    {
        auto Al = reinterpret_cast<unsigned short(*)[40]>(smem);
        auto Bl = reinterpret_cast<unsigned short(*)[40]>(smem + 10240);
        *reinterpret_cast<uint4*>(&Al[row][cb])     = ra0;
        *reinterpret_cast<uint4*>(&Al[row][cb + 8]) = ra1;
        *reinterpret_cast<uint4*>(&Bl[row][cb])     = rb0;
        *reinterpret_cast<uint4*>(&Bl[row][cb + 8]) = rb1;
    }

    for (int it = 0; it < 16; ++it) {
        __syncthreads();
        const int k0 = it * 32;
        if (it < 15) {
            ra0 = *reinterpret_cast<const uint4*>(ap + k0 + 32);
            ra1 = *reinterpret_cast<const uint4*>(ap + k0 + 40);
            rb0 = *reinterpret_cast<const uint4*>(bp + k0 + 32);
            rb1 = *reinterpret_cast<const uint4*>(bp + k0 + 40);
        }

        auto Al = reinterpret_cast<unsigned short(*)[40]>(smem + (it & 1) * 20480);
        auto Bl = reinterpret_cast<unsigned short(*)[40]>(smem + (it & 1) * 20480 + 10240);

        short8 af[4], bf[4];
        #pragma unroll
        for (int ti = 0; ti < 4; ++ti)
            af[ti] = *reinterpret_cast<const short8*>(&Al[wr * 64 + ti * 16 + l16][quad * 8]);
        #pragma unroll
        for (int tj = 0; tj < 4; ++tj)
            bf[tj] = *reinterpret_cast<const short8*>(&Bl[wc * 64 + tj * 16 + l16][quad * 8]);
        #pragma unroll
        for (int ti = 0; ti < 4; ++ti)
            #pragma unroll
            for (int tj = 0; tj < 4; ++tj)
                acc[ti][tj] = __builtin_amdgcn_mfma_f32_16x16x32_bf16(af[ti], bf[tj], acc[ti][tj], 0, 0, 0);

        if (it < 15) {
            auto An = reinterpret_cast<unsigned short(*)[40]>(smem + ((it + 1) & 1) * 20480);
            auto Bn = reinterpret_cast<unsigned short(*)[40]>(smem + ((it + 1) & 1) * 20480 + 10240);
            *reinterpret_cast<uint4*>(&An[row][cb])     = ra0;
            *reinterpret_cast<uint4*>(&An[row][cb + 8]) = ra1;
            *reinterpret_cast<uint4*>(&Bn[row][cb])     = rb0;
            *reinterpret_cast<uint4*>(&Bn[row][cb + 8]) = rb1;
        }
    }

    if (EPI == 0) {
        unsigned short* WS = (unsigned short*)outp;
        unsigned short* Qb  = WS;
        unsigned short* Kb  = WS + 4194304;
        unsigned short* Vtb = WS + 8388608;
        const int which = n0 >> 9;
        const int h = ((n0 + wc * 64) >> 6) & 7;

        if (which == 2) {
            auto Tr = reinterpret_cast<unsigned short(*)[80]>(smem);   // [256][80]
            __syncthreads();
            #pragma unroll
            for (int ti = 0; ti < 4; ++ti)
                #pragma unroll
                for (int tj = 0; tj < 4; ++tj) {
                    unsigned int lo = pk_bf16(acc[ti][tj][0], acc[ti][tj][1]);
                    unsigned int hi = pk_bf16(acc[ti][tj][2], acc[ti][tj][3]);
                    *reinterpret_cast<uint2*>(&Tr[(wave << 6) + tj * 16 + l16][ti * 16 + quad * 4])
                        = make_uint2(lo, hi);
                }
            const int b = m0 >> 12;
            const int bh = b * 8 + h;
            const int t0g = (m0 & 4095) + wr * 64;
            const int tseg = (lane & 7) * 8;
            #pragma unroll
            for (int p = 0; p < 8; ++p) {
                int dl = p * 8 + (lane >> 3);
                uint4 v = *reinterpret_cast<const uint4*>(&Tr[(wave << 6) + dl][tseg]);
                *reinterpret_cast<uint4*>(&Vtb[((size_t)(bh * 64 + dl)) * 4096 + t0g + tseg]) = v;
            }
        } else {
            const float sc = (which == 0) ? 0.18033688f : 1.0f;  // 0.125*log2(e)
            #pragma unroll
            for (int ti = 0; ti < 4; ++ti) {
                #pragma unroll
                for (int r = 0; r < 4; ++r) {
                    int m = m0 + wr * 64 + ti * 16 + quad * 4 + r;
                    int b = m >> 12, t = m & 4095;
                    int bh = b * 8 + h;
                    #pragma unroll
                    for (int tj = 0; tj < 4; ++tj) {
                        int d = tj * 16 + l16;
                        unsigned short val = f2bf(acc[ti][tj][r] * sc);
                        if (which == 0) Qb[((size_t)bh * 4096 + t) * 64 + d] = val;
                        else            Kb[((size_t)bh * 4096 + t) * 64 + d] = val;
                    }
                }
            }
        }
    } else {
        float* Out = (float*)outp;
        #pragma unroll
        for (int ti = 0; ti < 4; ++ti) {
            #pragma unroll
            for (int r = 0; r < 4; ++r) {
                int m = m0 + wr * 64 + ti * 16 + quad * 4 + r;
                #pragma unroll
                for (int tj = 0; tj < 4; ++tj) {
                    int n = n0 + wc * 64 + tj * 16 + l16;
                    Out[(size_t)m * 512 + n] = acc[ti][tj][r];
                }
            }
        }
    }
}

// ---------------- MFMA flash attention: 16 q-rows/wave + K/V LDS DOUBLE-BUFFER --------
// Block = 64 q-rows (4 waves), 1024 blocks, 256 threads. One __syncthreads per K-tile
// (r16 had two -> full vmcnt/lgkm drain each). Writes for tile kt+1 go to the idle
// buffer after the barrier (its readers finished in iter kt-1). Pc per-wave, no barrier.
// LDS 45 KB -> 3 blocks/CU (vs 4 grid-capped before): mild TLP loss vs halved drains.
__global__ __launch_bounds__(256) void attn_mfma(
    const unsigned short* __restrict__ Q,
    const unsigned short* __restrict__ K,
    const unsigned short* __restrict__ Vt,
    unsigned short* __restrict__ Y)
{
    __shared__ __align__(16) unsigned short Kc[2][64][72];
    __shared__ __align__(16) unsigned short Vc[2][64][72];
    __shared__ __align__(16) unsigned short Pc[4][16][72];

    const int tid  = threadIdx.x;
    const int wave = tid >> 6;
    const int lane = tid & 63;
    const int quad = lane >> 4;
    const int l16  = lane & 15;

    // balanced qb permutation: blocks {g*256+j*16+bh} get qb {j, 63-j, 16+j, 47-j}
    const int bid = blockIdx.x;
    const int bh = bid & 15;
    const int j  = (bid >> 4) & 15;
    const int g  = bid >> 8;
    const int qb = (g == 0) ? j : (g == 1) ? (63 - j) : (g == 2) ? (16 + j) : (47 - j);
    const int m0 = qb * 64;

    const unsigned short* Qp = Q  + (size_t)bh * (4096 * 64);
    const unsigned short* Kp = K  + (size_t)bh * (4096 * 64);
    const unsigned short* Vp = Vt + (size_t)bh * (64 * 4096);

    const int qrow = m0 + wave * 16 + l16;
    short8 qf[2];
    qf[0] = *reinterpret_cast<const short8*>(&Qp[(size_t)qrow * 64 + quad * 8]);
    qf[1] = *reinterpret_cast<const short8*>(&Qp[(size_t)qrow * 64 + 32 + quad * 8]);

    short8 ones;
    #pragma unroll
    for (int i = 0; i < 8; ++i) ones[i] = (short)0x3F80;

    floatx4 o[4] = {{0,0,0,0},{0,0,0,0},{0,0,0,0},{0,0,0,0}};
    floatx4 o4 = {0, 0, 0, 0};

    const int r0 = tid >> 3,          c0 = (tid & 7) * 8;
    const int r1 = (tid + 256) >> 3,  c1 = c0;

    uint4 rk0 = *reinterpret_cast<const uint4*>(&Kp[(size_t)r0 * 64 + c0]);
    uint4 rk1 = *reinterpret_cast<const uint4*>(&Kp[(size_t)r1 * 64 + c1]);
    uint4 rv0 = *reinterpret_cast<const uint4*>(&Vp[(size_t)r0 * 4096 + c0]);
    uint4 rv1 = *reinterpret_cast<const uint4*>(&Vp[(size_t)r1 * 4096 + c1]);
    // stage tile 0 into buffer 0 (reads ordered by the loop's first barrier)
    *reinterpret_cast<uint4*>(&Kc[0][r0][c0]) = rk0;
    *reinterpret_cast<uint4*>(&Kc[0][r1][c1]) = rk1;
    *reinterpret_cast<uint4*>(&Vc[0][r0][c0]) = rv0;
    *reinterpret_cast<uint4*>(&Vc[0][r1][c1]) = rv1;

    for (int kt = 0; kt <= qb; ++kt) {
        __syncthreads();   // buf[kt&1] writes visible; buf[(kt+1)&1] readers (iter kt-1) done
        const int cur = kt & 1;
        const int nxt = cur ^ 1;

        if (kt < qb) {     // prefetch next tile into registers (lands during compute)
            const int jn = (kt + 1) * 64;
            rk0 = *reinterpret_cast<const uint4*>(&Kp[(size_t)(jn + r0) * 64 + c0]);
            rk1 = *reinterpret_cast<const uint4*>(&Kp[(size_t)(jn + r1) * 64 + c1]);
            rv0 = *reinterpret_cast<const uint4*>(&Vp[(size_t)r0 * 4096 + jn + c0]);
            rv1 = *reinterpret_cast<const uint4*>(&Vp[(size_t)r1 * 4096 + jn + c1]);
        }

        float sv[4][4];
        #pragma unroll
        for (int ct = 0; ct < 4; ++ct) {
            floatx4 s = {0, 0, 0, 0};
            #pragma unroll
            for (int kk = 0; kk < 2; ++kk) {
                short8 a = *reinterpret_cast<const short8*>(&Kc[cur][ct * 16 + l16][kk * 32 + quad * 8]);
                s = __builtin_amdgcn_mfma_f32_16x16x32_bf16(a, qf[kk], s, 0, 0, 0);
            }
            sv[ct][0] = s[0]; sv[ct][1] = s[1]; sv[ct][2] = s[2]; sv[ct][3] = s[3];
        }

        if (kt == qb) {    // diagonal tile: causal mask
            #pragma unroll
            for (int ct = 0; ct < 4; ++ct)
                #pragma unroll
                for (int r = 0; r < 4; ++r) {
                    int keyl = ct * 16 + quad * 4 + r;
                    int ql   = wave * 16 + l16;
                    sv[ct][r] = (keyl <= ql) ? sv[ct][r] : -1e30f;
                }
        }
        #pragma unroll
        for (int ct = 0; ct < 4; ++ct)
            #pragma unroll
            for (int r = 0; r < 4; ++r)
                sv[ct][r] = __builtin_amdgcn_exp2f(sv[ct][r]);

        #pragma unroll
        for (int ct = 0; ct < 4; ++ct) {
            unsigned int d0 = pk_bf16(sv[ct][0], sv[ct][1]);
            unsigned int d1 = pk_bf16(sv[ct][2], sv[ct][3]);
            *reinterpret_cast<uint2*>(&Pc[wave][l16][ct * 16 + quad * 4]) = make_uint2(d0, d1);
        }

        short8 pa[2];
        pa[0] = *reinterpret_cast<const short8*>(&Pc[wave][l16][quad * 8]);
        pa[1] = *reinterpret_cast<const short8*>(&Pc[wave][l16][32 + quad * 8]);

        #pragma unroll
        for (int kk = 0; kk < 2; ++kk)
            o4 = __builtin_amdgcn_mfma_f32_16x16x32_bf16(pa[kk], ones, o4, 0, 0, 0);
        #pragma unroll
        for (int n = 0; n < 4; ++n) {
            #pragma unroll
            for (int kk = 0; kk < 2; ++kk) {
                short8 b = *reinterpret_cast<const short8*>(&Vc[cur][n * 16 + l16][kk * 32 + quad * 8]);
                o[n] = __builtin_amdgcn_mfma_f32_16x16x32_bf16(pa[kk], b, o[n], 0, 0, 0);
            }
        }

        if (kt < qb) {     // stage prefetched tile into the idle buffer
            *reinterpret_cast<uint4*>(&Kc[nxt][r0][c0]) = rk0;
            *reinterpret_cast<uint4*>(&Kc[nxt][r1][c1]) = rk1;
            *reinterpret_cast<uint4*>(&Vc[nxt][r0][c0]) = rv0;
            *reinterpret_cast<uint4*>(&Vc[nxt][r1][c1]) = rv1;
        }
    }

    const int b = bh >> 3, h = bh & 7;
    #pragma unroll
    for (int r = 0; r < 4; ++r) {
        float inv = 1.0f / o4[r];
        int t = m0 + wave * 16 + quad * 4 + r;
        #pragma unroll
        for (int n = 0; n < 4; ++n)
            Y[((size_t)(b * 4096 + t)) * 512 + h * 64 + n * 16 + l16] = f2bf(o[n][r] * inv);
    }
}

extern "C" void kernel_launch(void* const* d_in, const int* in_sizes, int n_in,
                              void* d_out, int out_size, void* d_ws, size_t ws_size,
                              hipStream_t stream) {
    const float* x  = (const float*)d_in[0];
    const float* Wa = (const float*)d_in[1];
    const float* Wp = (const float*)d_in[2];
    float* out = (float*)d_out;
    unsigned short* ws = (unsigned short*)d_ws;

    unsigned short* Qb  = ws;
    unsigned short* Kb  = ws + 4194304;
    unsigned short* Vtb = ws + 8388608;
    unsigned short* Yb  = ws + 12582912;
    unsigned short* WaT = Yb;                      // W_attn^T during QKV only
    unsigned short* WpT = Qb;                      // W_proj^T after attn (Q dead)
    unsigned short* xb  = (unsigned short*)d_out;  // x bf16; overwritten by proj

    prep_a<<<dim3(2816), dim3(256), 0, stream>>>(x, xb, Wa, WaT);
    mm_bt<0><<<dim3(64, 12), dim3(256), 0, stream>>>(xb, WaT, (void*)ws);
    attn_mfma<<<dim3(1024), dim3(256), 0, stream>>>(Qb, Kb, Vtb, Yb);
    transpose_wp<<<dim3(16, 16), dim3(256), 0, stream>>>(Wp, WpT);
    mm_bt<1><<<dim3(64, 4), dim3(256), 0, stream>>>(Yb, WpT, (void*)out);
}